// Round 1
// baseline (2363.923 us; speedup 1.0000x reference)
//
#include <hip/hip_runtime.h>
#include <math.h>

#define B_ 16
#define C_ 64
#define NEG_BIG (-1e30f)
#define POS_BIG (1e30f)
#define TR 128
#define TC 64

// ---------------- pyramid downsample: z max-pool pairs, t mean-pool pairs ----------------
__global__ __launch_bounds__(256) void downsample_kernel(
    const float* __restrict__ z1s, const float* __restrict__ z2s, const float* __restrict__ ts,
    float* __restrict__ z1d, float* __restrict__ z2d, float* __restrict__ td, int Td)
{
  int idx = blockIdx.x * blockDim.x + threadIdx.x;
  int total_z = B_ * Td * C_;
  if (idx < total_z) {
    int c  = idx & (C_ - 1);
    int bi = idx >> 6;
    int i  = bi % Td;
    int b  = bi / Td;
    int s  = (b * (2 * Td) + 2 * i) * C_ + c;
    z1d[idx] = fmaxf(z1s[s], z1s[s + C_]);
    z2d[idx] = fmaxf(z2s[s], z2s[s + C_]);
  } else {
    int k = idx - total_z;
    if (k < B_ * Td) {
      int i = k % Td;
      int b = k / Td;
      int s = b * (2 * Td) + 2 * i;
      td[k] = 0.5f * (ts[s] + ts[s + 1]);
    }
  }
}

// ---------------- instance contrastive loss (one thread per row) ----------------
// Top-16 nearest |t| neighbors across the 15 other (sorted) sequences via
// binary search + 15-way pointer merge, then 33 dot products -> lse - pos.
__global__ __launch_bounds__(64) void instance_kernel(
    const float* __restrict__ z1, const float* __restrict__ z2, const float* __restrict__ t,
    float* __restrict__ out, int T, int lgT, float scale)
{
  int n = blockIdx.x * 64 + threadIdx.x;
  int N = B_ * T;
  float lossn = 0.f;
  if (n < N) {
    int nbr[16];   // element offsets (row*64)
    if (T == 1) {
      #pragma unroll
      for (int j = 0; j < 16; j++) nbr[j] = j * C_;   // top-16 of 16 = everything (incl. self)
    } else {
      int bq = n >> lgT;
      float q = t[n];
      int Ls[15], Rs[15];
      float dLs[15], dRs[15];
      #pragma unroll
      for (int s = 0; s < 15; s++) {
        int bs = s + (s >= bq ? 1 : 0);
        const float* tb = t + bs * T;
        int l = 0, r = T;
        while (l < r) { int m = (l + r) >> 1; if (tb[m] < q) l = m + 1; else r = m; }
        Ls[s] = l - 1; Rs[s] = l;
        dLs[s] = (l - 1 >= 0) ? (q - tb[l - 1]) : POS_BIG;
        dRs[s] = (l < T)      ? (tb[l] - q)     : POS_BIG;
      }
      #pragma unroll
      for (int j = 0; j < 16; j++) {
        float best = POS_BIG; int sb = 0;
        #pragma unroll
        for (int s = 0; s < 15; s++) {
          float c = fminf(dLs[s], dRs[s]);
          bool better = c < best;
          best = better ? c : best;
          sb   = better ? s : sb;
        }
        int pick = 0;
        #pragma unroll
        for (int s = 0; s < 15; s++) {
          if (s == sb) {
            int bs = s + (s >= bq ? 1 : 0);
            const float* tb = t + bs * T;
            bool takeL = dLs[s] <= dRs[s];
            if (takeL) {
              pick = bs * T + Ls[s];
              Ls[s] -= 1;
              dLs[s] = (Ls[s] >= 0) ? (q - tb[Ls[s]]) : POS_BIG;
            } else {
              pick = bs * T + Rs[s];
              Rs[s] += 1;
              dRs[s] = (Rs[s] < T) ? (tb[Rs[s]] - q) : POS_BIG;
            }
          }
        }
        nbr[j] = pick * C_;
      }
    }
    const float* z1n = z1 + n * C_;
    const float* z2n = z2 + n * C_;
    float pos = 0.f;
    float a11[16], a12[16];
    #pragma unroll
    for (int j = 0; j < 16; j++) { a11[j] = 0.f; a12[j] = 0.f; }
    #pragma unroll 4
    for (int c4 = 0; c4 < 16; c4++) {
      float4 a = *(const float4*)(z1n + c4 * 4);
      float4 p = *(const float4*)(z2n + c4 * 4);
      pos += a.x * p.x + a.y * p.y + a.z * p.z + a.w * p.w;
      #pragma unroll
      for (int j = 0; j < 16; j++) {
        float4 u = *(const float4*)(z1 + nbr[j] + c4 * 4);
        float4 v = *(const float4*)(z2 + nbr[j] + c4 * 4);
        a11[j] += a.x * u.x + a.y * u.y + a.z * u.z + a.w * u.w;
        a12[j] += a.x * v.x + a.y * v.y + a.z * v.z + a.w * v.w;
      }
    }
    float m = pos;
    #pragma unroll
    for (int j = 0; j < 16; j++) m = fmaxf(m, fmaxf(a11[j], a12[j]));
    float se = expf(pos - m);
    #pragma unroll
    for (int j = 0; j < 16; j++) se += expf(a11[j] - m) + expf(a12[j] - m);
    lossn = (m + logf(se)) - pos;
  }
  #pragma unroll
  for (int off = 32; off; off >>= 1) lossn += __shfl_down(lossn, off, 64);
  if (threadIdx.x == 0) atomicAdd(out, lossn * scale);
}

// ---------------- temporal contrastive loss ----------------
// Per batch b: sim = zc zc^T (zc = [z1[b]; z2[b]], 2T x 64). Flash-style online
// row logsumexp excluding diag; capture positives sim[i,T+i], sim[T+i,i].
// Block: 128 rows x (64-col tiles), 256 threads, 8x4 register tile each.
__global__ __launch_bounds__(256) void temporal_kernel(
    const float* __restrict__ z1, const float* __restrict__ z2,
    float* __restrict__ out, int T, float scale)
{
  __shared__ float As[C_][TR + 4];   // c-major: As[c][row]
  __shared__ float Bs[C_][TC + 4];
  __shared__ float Ms[TR], Ss[TR], Ps[TR];
  __shared__ float red[4];

  int b = blockIdx.y;
  int TT = 2 * T;
  int rbase = blockIdx.x * TR;
  int tid = threadIdx.x;
  const float* zb1 = z1 + b * T * C_;
  const float* zb2 = z2 + b * T * C_;

  for (int e4 = tid; e4 < TR * 16; e4 += 256) {
    int r = e4 >> 4, c4 = e4 & 15;
    int gr = rbase + r;
    float4 v = make_float4(0.f, 0.f, 0.f, 0.f);
    if (gr < TT) {
      const float* src = (gr < T) ? (zb1 + gr * C_) : (zb2 + (gr - T) * C_);
      v = *(const float4*)(src + c4 * 4);
    }
    As[c4 * 4 + 0][r] = v.x; As[c4 * 4 + 1][r] = v.y;
    As[c4 * 4 + 2][r] = v.z; As[c4 * 4 + 3][r] = v.w;
  }
  if (tid < TR) { Ms[tid] = NEG_BIG; Ss[tid] = 0.f; Ps[tid] = 0.f; }
  __syncthreads();

  int ty = tid >> 4, tx = tid & 15;
  int lr0 = ty * 8, lc0 = tx * 4;
  int nct = (TT + TC - 1) / TC;

  for (int ct = 0; ct < nct; ct++) {
    int cbase = ct * TC;
    for (int e4 = tid; e4 < TC * 16; e4 += 256) {
      int r = e4 >> 4, c4 = e4 & 15;
      int gr = cbase + r;
      float4 v = make_float4(0.f, 0.f, 0.f, 0.f);
      if (gr < TT) {
        const float* src = (gr < T) ? (zb1 + gr * C_) : (zb2 + (gr - T) * C_);
        v = *(const float4*)(src + c4 * 4);
      }
      Bs[c4 * 4 + 0][r] = v.x; Bs[c4 * 4 + 1][r] = v.y;
      Bs[c4 * 4 + 2][r] = v.z; Bs[c4 * 4 + 3][r] = v.w;
    }
    __syncthreads();

    float acc[8][4];
    #pragma unroll
    for (int i = 0; i < 8; i++)
      #pragma unroll
      for (int j = 0; j < 4; j++) acc[i][j] = 0.f;

    #pragma unroll 4
    for (int c = 0; c < C_; c++) {
      float4 a0 = *(const float4*)&As[c][lr0];
      float4 a1 = *(const float4*)&As[c][lr0 + 4];
      float4 bv = *(const float4*)&Bs[c][lc0];
      float ar[8] = {a0.x, a0.y, a0.z, a0.w, a1.x, a1.y, a1.z, a1.w};
      float br[4] = {bv.x, bv.y, bv.z, bv.w};
      #pragma unroll
      for (int i = 0; i < 8; i++)
        #pragma unroll
        for (int j = 0; j < 4; j++) acc[i][j] += ar[i] * br[j];
    }

    #pragma unroll
    for (int i = 0; i < 8; i++) {
      int lr = lr0 + i;
      int r = rbase + lr;
      int pc = (r < T) ? (r + T) : (r - T);
      float m_p = NEG_BIG, s_p = 0.f;
      float e[4];
      #pragma unroll
      for (int j = 0; j < 4; j++) {
        int cg = cbase + lc0 + j;
        float v = acc[i][j];
        if (r < TT && cg == pc) Ps[lr] = v;        // unique writer per row overall
        bool valid = (cg < TT) && (cg != r);
        e[j] = valid ? v : NEG_BIG;
        m_p = fmaxf(m_p, e[j]);
      }
      #pragma unroll
      for (int j = 0; j < 4; j++) s_p += expf(e[j] - m_p);
      #pragma unroll
      for (int msk = 1; msk < 16; msk <<= 1) {
        float mo = __shfl_xor(m_p, msk, 16);
        float so = __shfl_xor(s_p, msk, 16);
        float d = m_p - mo;
        float ex = expf(-fabsf(d));
        if (d >= 0.f) { s_p = s_p + so * ex; }
        else          { s_p = so + s_p * ex; m_p = mo; }
      }
      if (tx == 0 && r < TT) {
        float M = Ms[lr], S = Ss[lr];
        float d = M - m_p;
        float ex = expf(-fabsf(d));
        if (d >= 0.f) { Ss[lr] = S + s_p * ex; }
        else          { Ss[lr] = s_p + S * ex; Ms[lr] = m_p; }
      }
    }
    __syncthreads();
  }

  float val = 0.f;
  if (tid < TR) {
    int r = rbase + tid;
    if (r < TT) val = Ms[tid] + logf(Ss[tid]) - Ps[tid];
  }
  #pragma unroll
  for (int off = 32; off; off >>= 1) val += __shfl_down(val, off, 64);
  if ((tid & 63) == 0) red[tid >> 6] = val;
  __syncthreads();
  if (tid == 0) atomicAdd(out, (red[0] + red[1] + red[2] + red[3]) * scale);
}

// ---------------- host side ----------------
extern "C" void kernel_launch(void* const* d_in, const int* in_sizes, int n_in,
                              void* d_out, int out_size, void* d_ws, size_t ws_size,
                              hipStream_t stream)
{
  (void)in_sizes; (void)n_in; (void)out_size; (void)ws_size;
  const float* z1_0 = (const float*)d_in[0];
  const float* z2_0 = (const float*)d_in[1];
  const float* t_0  = (const float*)d_in[2];
  float* out = (float*)d_out;
  float* ws  = (float*)d_ws;

  const float* z1L[11]; const float* z2L[11]; const float* tL[11];
  float* z1Lw[11]; float* z2Lw[11]; float* tLw[11];
  z1L[0] = z1_0; z2L[0] = z2_0; tL[0] = t_0;
  size_t off = 0;
  for (int l = 1; l <= 10; l++) {
    int T = 1024 >> l;
    z1Lw[l] = ws + off; off += (size_t)16 * T * 64;
    z2Lw[l] = ws + off; off += (size_t)16 * T * 64;
    tLw[l]  = ws + off; off += (size_t)16 * T;
    z1L[l] = z1Lw[l]; z2L[l] = z2Lw[l]; tL[l] = tLw[l];
  }

  hipMemsetAsync(d_out, 0, sizeof(float), stream);

  const float inv_d = 1.0f / 11.0f;   // d = 11 levels
  for (int l = 0; l <= 10; l++) {
    int T = 1024 >> l;
    if (l > 0) {
      int total = 16 * T * 64 + 16 * T;
      int blocks = (total + 255) / 256;
      hipLaunchKernelGGL(downsample_kernel, dim3(blocks), dim3(256), 0, stream,
                         z1L[l - 1], z2L[l - 1], tL[l - 1], z1Lw[l], z2Lw[l], tLw[l], T);
    }
    int N = 16 * T;
    int lgT = 10 - l;
    float iscale = 0.5f * inv_d / (float)N;
    hipLaunchKernelGGL(instance_kernel, dim3((N + 63) / 64), dim3(64), 0, stream,
                       z1L[l], z2L[l], tL[l], out, T, lgT, iscale);
    if (T > 1) {
      float tscale = 0.5f * inv_d / (2.0f * 16.0f * (float)T);
      hipLaunchKernelGGL(temporal_kernel, dim3((2 * T + TR - 1) / TR, 16), dim3(256), 0, stream,
                         z1L[l], z2L[l], out, T, tscale);
    }
  }
}

// Round 2
// 2040.101 us; speedup vs baseline: 1.1587x; 1.1587x over previous
//
#include <hip/hip_runtime.h>
#include <hip/hip_bf16.h>
#include <math.h>

#define B_ 16
#define C_ 64
#define NEG_BIG (-1e30f)
#define POS_BIG (1e30f)

typedef __attribute__((ext_vector_type(8))) short bf16x8;
typedef __attribute__((ext_vector_type(4))) float f32x4;

__device__ __forceinline__ short f2bf(float x) {
  __hip_bfloat16 h = __float2bfloat16(x);
  return *reinterpret_cast<short*>(&h);
}

// Load 8 consecutive K-elements of row `row` of zc=[z1;z2] as bf16x8.
// Same function used for A and B fragments (layout-symmetry trick for Z*Z^T).
__device__ __forceinline__ bf16x8 ld8(const float* __restrict__ zb1,
                                      const float* __restrict__ zb2,
                                      int T, int row, int k0) {
  const float* src = (row < T) ? (zb1 + row * C_ + k0) : (zb2 + (row - T) * C_ + k0);
  float4 u = *(const float4*)src;
  float4 v = *(const float4*)(src + 4);
  bf16x8 f;
  f[0] = f2bf(u.x); f[1] = f2bf(u.y); f[2] = f2bf(u.z); f[3] = f2bf(u.w);
  f[4] = f2bf(v.x); f[5] = f2bf(v.y); f[6] = f2bf(v.z); f[7] = f2bf(v.w);
  return f;
}

// ---------------- pyramid downsample: z max-pool pairs, t mean-pool pairs ----------------
__global__ __launch_bounds__(256) void downsample_kernel(
    const float* __restrict__ z1s, const float* __restrict__ z2s, const float* __restrict__ ts,
    float* __restrict__ z1d, float* __restrict__ z2d, float* __restrict__ td, int Td)
{
  int idx = blockIdx.x * blockDim.x + threadIdx.x;
  int total_z = B_ * Td * C_;
  if (idx < total_z) {
    int c  = idx & (C_ - 1);
    int bi = idx >> 6;
    int i  = bi % Td;
    int b  = bi / Td;
    int s  = (b * (2 * Td) + 2 * i) * C_ + c;
    z1d[idx] = fmaxf(z1s[s], z1s[s + C_]);
    z2d[idx] = fmaxf(z2s[s], z2s[s + C_]);
  } else {
    int k = idx - total_z;
    if (k < B_ * Td) {
      int i = k % Td;
      int b = k / Td;
      int s = b * (2 * Td) + 2 * i;
      td[k] = 0.5f * (ts[s] + ts[s + 1]);
    }
  }
}

// ---------------- instance contrastive loss ----------------
// t staged in LDS; 15 branchless binary searches interleaved (k-step outer) for ILP;
// 15-way pointer merge for top-16 neighbors; 33 dot products -> lse - pos.
__global__ __launch_bounds__(256) void instance_kernel(
    const float* __restrict__ z1, const float* __restrict__ z2, const float* __restrict__ t,
    float* __restrict__ out, int T, int lgT, float scale)
{
  extern __shared__ float ts[];   // 16*T floats
  int N = B_ * T;
  for (int i = threadIdx.x; i < N; i += 256) ts[i] = t[i];
  __syncthreads();

  int n = blockIdx.x * 256 + threadIdx.x;
  float lossn = 0.f;
  if (n < N) {
    int nbr[16];
    if (T == 1) {
      #pragma unroll
      for (int j = 0; j < 16; j++) nbr[j] = j * C_;   // top-16 of 16 = everything (incl. self)
    } else {
      int bq = n >> lgT;
      float q = ts[n];
      int l[15];
      #pragma unroll
      for (int s = 0; s < 15; s++) l[s] = 0;
      // branchless lower_bound, fixed lgT trips, 15 independent LDS loads per step
      for (int k = T >> 1; k; k >>= 1) {
        #pragma unroll
        for (int s = 0; s < 15; s++) {
          int bs = s + (s >= bq ? 1 : 0);
          l[s] += (ts[(bs << lgT) + l[s] + k - 1] < q) ? k : 0;
        }
      }
      int Ls[15], Rs[15];
      float dLs[15], dRs[15];
      #pragma unroll
      for (int s = 0; s < 15; s++) {
        int bs = s + (s >= bq ? 1 : 0);
        const float* tb = ts + (bs << lgT);
        Ls[s] = l[s] - 1; Rs[s] = l[s];
        dLs[s] = (l[s] >= 1) ? (q - tb[l[s] - 1]) : POS_BIG;
        dRs[s] = (l[s] < T) ? (tb[l[s]] - q) : POS_BIG;
      }
      #pragma unroll
      for (int j = 0; j < 16; j++) {
        float best = POS_BIG; int sb = 0;
        #pragma unroll
        for (int s = 0; s < 15; s++) {
          float c = fminf(dLs[s], dRs[s]);
          bool better = c < best;
          best = better ? c : best;
          sb   = better ? s : sb;
        }
        int pick = 0;
        #pragma unroll
        for (int s = 0; s < 15; s++) {
          if (s == sb) {
            int bs = s + (s >= bq ? 1 : 0);
            const float* tb = ts + (bs << lgT);
            if (dLs[s] <= dRs[s]) {
              pick = (bs << lgT) + Ls[s];
              Ls[s] -= 1;
              dLs[s] = (Ls[s] >= 0) ? (q - tb[Ls[s]]) : POS_BIG;
            } else {
              pick = (bs << lgT) + Rs[s];
              Rs[s] += 1;
              dRs[s] = (Rs[s] < T) ? (tb[Rs[s]] - q) : POS_BIG;
            }
          }
        }
        nbr[j] = pick * C_;
      }
    }
    const float* z1n = z1 + n * C_;
    const float* z2n = z2 + n * C_;
    float pos = 0.f;
    float a11[16], a12[16];
    #pragma unroll
    for (int j = 0; j < 16; j++) { a11[j] = 0.f; a12[j] = 0.f; }
    #pragma unroll 2
    for (int c4 = 0; c4 < 16; c4++) {
      float4 a = *(const float4*)(z1n + c4 * 4);
      float4 p = *(const float4*)(z2n + c4 * 4);
      pos += a.x * p.x + a.y * p.y + a.z * p.z + a.w * p.w;
      #pragma unroll
      for (int j = 0; j < 16; j++) {
        float4 u = *(const float4*)(z1 + nbr[j] + c4 * 4);
        float4 v = *(const float4*)(z2 + nbr[j] + c4 * 4);
        a11[j] += a.x * u.x + a.y * u.y + a.z * u.z + a.w * u.w;
        a12[j] += a.x * v.x + a.y * v.y + a.z * v.z + a.w * v.w;
      }
    }
    float m = pos;
    #pragma unroll
    for (int j = 0; j < 16; j++) m = fmaxf(m, fmaxf(a11[j], a12[j]));
    float se = __expf(pos - m);
    #pragma unroll
    for (int j = 0; j < 16; j++) se += __expf(a11[j] - m) + __expf(a12[j] - m);
    lossn = (m + __logf(se)) - pos;
  }
  #pragma unroll
  for (int off = 32; off; off >>= 1) lossn += __shfl_down(lossn, off, 64);
  if ((threadIdx.x & 63) == 0) atomicAdd(out, lossn * scale);
}

// ---------------- temporal contrastive loss, bf16 MFMA ----------------
// Per batch: sim = zc zc^T via mfma_f32_16x16x32_bf16 (zc = [z1[b]; z2[b]], 2T x 64).
// Each wave owns 16 rows; loops 64-col chunks (4 tiles x 2 K-steps = 8 MFMA).
// Per-lane online logsumexp over its own column subset; one 16-lane butterfly at end.
__global__ __launch_bounds__(256) void temporal_kernel(
    const float* __restrict__ z1, const float* __restrict__ z2,
    float* __restrict__ out, int T, float scale)
{
  int b = blockIdx.y;
  int TT = 2 * T;
  const float* zb1 = z1 + b * T * C_;
  const float* zb2 = z2 + b * T * C_;
  int wv = threadIdx.x >> 6;
  int lane = threadIdx.x & 63;
  int lo = lane & 15, hi = lane >> 4;
  int rowbase = blockIdx.x * 64 + wv * 16;

  // A fragments: row = rowbase + lo, k = kc*32 + hi*8 + i
  int ar = rowbase + lo; if (ar >= TT) ar = 0;          // clamp; masked in epilogue
  bf16x8 a0 = ld8(zb1, zb2, T, ar, hi * 8);
  bf16x8 a1 = ld8(zb1, zb2, T, ar, 32 + hi * 8);

  float m[4], s[4], pos[4];
  #pragma unroll
  for (int sl = 0; sl < 4; sl++) { m[sl] = NEG_BIG; s[sl] = 0.f; pos[sl] = 0.f; }

  int nch = (TT + 63) >> 6;
  for (int ch = 0; ch < nch; ch++) {
    int cb = ch * 64;
    f32x4 acc[4];
    #pragma unroll
    for (int tt = 0; tt < 4; tt++) {
      int br = cb + tt * 16 + lo; if (br >= TT) br = 0;  // clamp; masked below
      bf16x8 b0 = ld8(zb1, zb2, T, br, hi * 8);
      bf16x8 b1 = ld8(zb1, zb2, T, br, 32 + hi * 8);
      f32x4 c = {0.f, 0.f, 0.f, 0.f};
      c = __builtin_amdgcn_mfma_f32_16x16x32_bf16(a0, b0, c, 0, 0, 0);
      c = __builtin_amdgcn_mfma_f32_16x16x32_bf16(a1, b1, c, 0, 0, 0);
      acc[tt] = c;
    }
    // C/D layout: col = cb + tt*16 + lo, row(local) = hi*4 + sl
    #pragma unroll
    for (int sl = 0; sl < 4; sl++) {
      int r = rowbase + hi * 4 + sl;
      int pc = (r < T) ? (r + T) : (r - T);
      float v[4]; float vmax = NEG_BIG;
      #pragma unroll
      for (int tt = 0; tt < 4; tt++) {
        int cg = cb + tt * 16 + lo;
        float x = acc[tt][sl];
        if (r < TT && cg == pc) pos[sl] += x;            // captured exactly once
        bool excl = (cg >= TT) || (cg == r);
        x = excl ? NEG_BIG : x;
        v[tt] = x; vmax = fmaxf(vmax, x);
      }
      if (vmax > -1e29f) {
        float mn = fmaxf(m[sl], vmax);
        float ss = s[sl] * __expf(m[sl] - mn);
        #pragma unroll
        for (int tt = 0; tt < 4; tt++) ss += __expf(v[tt] - mn);
        s[sl] = ss; m[sl] = mn;
      }
    }
  }

  // merge (m,s,pos) across the 16 lanes (lo) holding different column subsets
  #pragma unroll
  for (int msk = 1; msk < 16; msk <<= 1) {
    #pragma unroll
    for (int sl = 0; sl < 4; sl++) {
      float mo = __shfl_xor(m[sl], msk, 16);
      float so = __shfl_xor(s[sl], msk, 16);
      float po = __shfl_xor(pos[sl], msk, 16);
      float mn = fmaxf(m[sl], mo);
      s[sl] = s[sl] * __expf(m[sl] - mn) + so * __expf(mo - mn);
      m[sl] = mn;
      pos[sl] += po;
    }
  }

  float val = 0.f;
  if (lo == 0) {
    #pragma unroll
    for (int sl = 0; sl < 4; sl++) {
      int r = rowbase + hi * 4 + sl;
      if (r < TT) val += m[sl] + __logf(s[sl]) - pos[sl];
    }
  }
  #pragma unroll
  for (int off = 32; off; off >>= 1) val += __shfl_down(val, off, 64);
  if (lane == 0) atomicAdd(out, val * scale);
}

// ---------------- host side ----------------
extern "C" void kernel_launch(void* const* d_in, const int* in_sizes, int n_in,
                              void* d_out, int out_size, void* d_ws, size_t ws_size,
                              hipStream_t stream)
{
  (void)in_sizes; (void)n_in; (void)out_size; (void)ws_size;
  const float* z1_0 = (const float*)d_in[0];
  const float* z2_0 = (const float*)d_in[1];
  const float* t_0  = (const float*)d_in[2];
  float* out = (float*)d_out;
  float* ws  = (float*)d_ws;

  const float* z1L[11]; const float* z2L[11]; const float* tL[11];
  float* z1Lw[11]; float* z2Lw[11]; float* tLw[11];
  z1L[0] = z1_0; z2L[0] = z2_0; tL[0] = t_0;
  size_t off = 0;
  for (int l = 1; l <= 10; l++) {
    int T = 1024 >> l;
    z1Lw[l] = ws + off; off += (size_t)16 * T * 64;
    z2Lw[l] = ws + off; off += (size_t)16 * T * 64;
    tLw[l]  = ws + off; off += (size_t)16 * T;
    z1L[l] = z1Lw[l]; z2L[l] = z2Lw[l]; tL[l] = tLw[l];
  }

  hipMemsetAsync(d_out, 0, sizeof(float), stream);

  const float inv_d = 1.0f / 11.0f;   // d = 11 levels
  for (int l = 0; l <= 10; l++) {
    int T = 1024 >> l;
    if (l > 0) {
      int total = 16 * T * 64 + 16 * T;
      int blocks = (total + 255) / 256;
      hipLaunchKernelGGL(downsample_kernel, dim3(blocks), dim3(256), 0, stream,
                         z1L[l - 1], z2L[l - 1], tL[l - 1], z1Lw[l], z2Lw[l], tLw[l], T);
    }
    int N = 16 * T;
    int lgT = 10 - l;
    float iscale = 0.5f * inv_d / (float)N;
    hipLaunchKernelGGL(instance_kernel, dim3((N + 255) / 256), dim3(256), 16 * T * 4, stream,
                       z1L[l], z2L[l], tL[l], out, T, lgT, iscale);
    if (T > 1) {
      float tscale = 0.5f * inv_d / (2.0f * 16.0f * (float)T);
      hipLaunchKernelGGL(temporal_kernel, dim3((2 * T + 63) / 64, 16), dim3(256), 0, stream,
                         z1L[l], z2L[l], out, T, tscale);
    }
  }
}

// Round 3
// 615.912 us; speedup vs baseline: 3.8381x; 3.3123x over previous
//
#include <hip/hip_runtime.h>
#include <hip/hip_bf16.h>
#include <math.h>

#define B_ 16
#define C_ 64
#define NEG_BIG (-1e30f)
#define POS_BIG (1e30f)

typedef __attribute__((ext_vector_type(8))) short bf16x8;
typedef __attribute__((ext_vector_type(4))) float f32x4;

__device__ __forceinline__ short f2bf(float x) {
  __hip_bfloat16 h = __float2bfloat16(x);
  return *reinterpret_cast<short*>(&h);
}

__device__ __forceinline__ bf16x8 ld8(const float* __restrict__ zb1,
                                      const float* __restrict__ zb2,
                                      int T, int row, int k0) {
  const float* src = (row < T) ? (zb1 + row * C_ + k0) : (zb2 + (row - T) * C_ + k0);
  float4 u = *(const float4*)src;
  float4 v = *(const float4*)(src + 4);
  bf16x8 f;
  f[0] = f2bf(u.x); f[1] = f2bf(u.y); f[2] = f2bf(u.z); f[3] = f2bf(u.w);
  f[4] = f2bf(v.x); f[5] = f2bf(v.y); f[6] = f2bf(v.z); f[7] = f2bf(v.w);
  return f;
}

// ---------------- pyramid downsample ----------------
__global__ __launch_bounds__(256) void downsample_kernel(
    const float* __restrict__ z1s, const float* __restrict__ z2s, const float* __restrict__ ts,
    float* __restrict__ z1d, float* __restrict__ z2d, float* __restrict__ td, int Td)
{
  int idx = blockIdx.x * blockDim.x + threadIdx.x;
  int total_z = B_ * Td * C_;
  if (idx < total_z) {
    int c  = idx & (C_ - 1);
    int bi = idx >> 6;
    int i  = bi % Td;
    int b  = bi / Td;
    int s  = (b * (2 * Td) + 2 * i) * C_ + c;
    z1d[idx] = fmaxf(z1s[s], z1s[s + C_]);
    z2d[idx] = fmaxf(z2s[s], z2s[s + C_]);
  } else {
    int k = idx - total_z;
    if (k < B_ * Td) {
      int i = k % Td;
      int b = k / Td;
      int s = b * (2 * Td) + 2 * i;
      td[k] = 0.5f * (ts[s] + ts[s + 1]);
    }
  }
}

// ---------------- instance contrastive loss (3-phase, wave-cooperative) ----------------
// A0: 64 rows x 15 seqs parallel branchless binary searches (global t, L2).
// A1: per-row 16-step pointer merge, state in LDS (dynamic LDS idx, no scratch).
// B : 16 lanes cooperate per row -> coalesced 256B neighbor-row loads, butterfly reduce.
__global__ __launch_bounds__(256) void instance_kernel(
    const float* __restrict__ z1, const float* __restrict__ z2, const float* __restrict__ t,
    float* __restrict__ out, int T, int lgT, float scale)
{
  __shared__ float dmin[64 * 17], dLl[64 * 17], dRl[64 * 17];
  __shared__ int   Lp[64 * 17], Rp[64 * 17];
  __shared__ int   nbrs[64][16];

  int tid = threadIdx.x;
  int rbase = blockIdx.x * 64;
  int N = B_ * T;

  if (T == 1) {
    for (int idx = tid; idx < 64 * 16; idx += 256)
      nbrs[idx >> 4][idx & 15] = idx & 15;      // all 16 rows incl. self
  } else {
    // ---- A0: parallel searches ----
    for (int idx = tid; idx < 64 * 16; idx += 256) {
      int r = idx >> 4, s = idx & 15;
      int n = rbase + r;
      if (s < 15 && n < N) {
        int bq = n >> lgT;
        float q = t[n];
        int bs = s + (s >= bq ? 1 : 0);
        const float* tb = t + (bs << lgT);
        int l = 0;
        for (int k = T >> 1; k; k >>= 1) l += (tb[l + k - 1] < q) ? k : 0;
        l += (tb[l] < q) ? 1 : 0;               // exact lower_bound incl. l==T
        float dl = (l >= 1) ? (q - tb[l - 1]) : POS_BIG;
        float dr = (l < T)  ? (tb[l] - q)     : POS_BIG;
        int o = r * 17 + s;
        Lp[o] = l - 1; Rp[o] = l;
        dLl[o] = dl; dRl[o] = dr; dmin[o] = fminf(dl, dr);
      }
    }
  }
  __syncthreads();

  int w = tid >> 6, lane = tid & 63;

  // ---- A1: per-row merge (16 lanes of each wave) ----
  if (T > 1 && lane < 16) {
    int r = w * 16 + lane;
    int n = rbase + r;
    if (n < N) {
      int bq = n >> lgT;
      float q = t[n];
      #pragma unroll 1
      for (int j = 0; j < 16; j++) {
        float best = dmin[r * 17]; int sb = 0;
        #pragma unroll
        for (int s = 1; s < 15; s++) {
          float c = dmin[r * 17 + s];
          bool lt = c < best; best = lt ? c : best; sb = lt ? s : sb;
        }
        int o = r * 17 + sb;
        int bs = sb + (sb >= bq ? 1 : 0);
        float dl = dLl[o], dr = dRl[o];
        if (dl <= dr) {
          int p = Lp[o];
          nbrs[r][j] = bs * T + p;
          int pn = p - 1; Lp[o] = pn;
          float nd = (pn >= 0) ? (q - t[bs * T + pn]) : POS_BIG;
          dLl[o] = nd; dmin[o] = fminf(nd, dr);
        } else {
          int p = Rp[o];
          nbrs[r][j] = bs * T + p;
          int pn = p + 1; Rp[o] = pn;
          float nd = (pn < T) ? (t[bs * T + pn] - q) : POS_BIG;
          dRl[o] = nd; dmin[o] = fminf(dl, nd);
        }
      }
    } else {
      #pragma unroll
      for (int j = 0; j < 16; j++) nbrs[r][j] = 0;   // safe, row masked in B
    }
  }
  __syncthreads();

  // ---- B: wave-cooperative dots ----
  int g = lane >> 4, sl = lane & 15;
  float loss = 0.f;
  #pragma unroll 1
  for (int rc = 0; rc < 4; rc++) {
    int r = w * 16 + rc * 4 + g;
    int n = rbase + r;
    bool act = n < N;
    int ns = act ? n : rbase;
    float4 za = *(const float4*)(z1 + (size_t)ns * C_ + sl * 4);
    float4 zp = *(const float4*)(z2 + (size_t)ns * C_ + sl * 4);
    float pos = za.x * zp.x + za.y * zp.y + za.z * zp.z + za.w * zp.w;
    float a11[16], a12[16];
    #pragma unroll
    for (int j = 0; j < 16; j++) {
      int nb = nbrs[r][j];
      float4 uu = *(const float4*)(z1 + (size_t)nb * C_ + sl * 4);
      float4 vv = *(const float4*)(z2 + (size_t)nb * C_ + sl * 4);
      a11[j] = za.x * uu.x + za.y * uu.y + za.z * uu.z + za.w * uu.w;
      a12[j] = za.x * vv.x + za.y * vv.y + za.z * vv.z + za.w * vv.w;
    }
    #pragma unroll
    for (int msk = 1; msk < 16; msk <<= 1) {
      pos += __shfl_xor(pos, msk, 16);
      #pragma unroll
      for (int j = 0; j < 16; j++) {
        a11[j] += __shfl_xor(a11[j], msk, 16);
        a12[j] += __shfl_xor(a12[j], msk, 16);
      }
    }
    if (sl == 0 && act) {
      float m = pos;
      #pragma unroll
      for (int j = 0; j < 16; j++) m = fmaxf(m, fmaxf(a11[j], a12[j]));
      float se = __expf(pos - m);
      #pragma unroll
      for (int j = 0; j < 16; j++) se += __expf(a11[j] - m) + __expf(a12[j] - m);
      loss += (m + __logf(se)) - pos;
    }
  }
  #pragma unroll
  for (int off = 32; off; off >>= 1) loss += __shfl_down(loss, off, 64);
  if (lane == 0) atomicAdd(out, loss * scale);
}

// ---------------- temporal contrastive loss, bf16 MFMA ----------------
__global__ __launch_bounds__(256) void temporal_kernel(
    const float* __restrict__ z1, const float* __restrict__ z2,
    float* __restrict__ out, int T, float scale)
{
  int b = blockIdx.y;
  int TT = 2 * T;
  const float* zb1 = z1 + b * T * C_;
  const float* zb2 = z2 + b * T * C_;
  int wv = threadIdx.x >> 6;
  int lane = threadIdx.x & 63;
  int lo = lane & 15, hi = lane >> 4;
  int rowbase = blockIdx.x * 64 + wv * 16;

  int ar = rowbase + lo; if (ar >= TT) ar = 0;
  bf16x8 a0 = ld8(zb1, zb2, T, ar, hi * 8);
  bf16x8 a1 = ld8(zb1, zb2, T, ar, 32 + hi * 8);

  float m[4], s[4], pos[4];
  #pragma unroll
  for (int sl = 0; sl < 4; sl++) { m[sl] = NEG_BIG; s[sl] = 0.f; pos[sl] = 0.f; }

  int nch = (TT + 63) >> 6;
  for (int ch = 0; ch < nch; ch++) {
    int cb = ch * 64;
    f32x4 acc[4];
    #pragma unroll
    for (int tt = 0; tt < 4; tt++) {
      int br = cb + tt * 16 + lo; if (br >= TT) br = 0;
      bf16x8 b0 = ld8(zb1, zb2, T, br, hi * 8);
      bf16x8 b1 = ld8(zb1, zb2, T, br, 32 + hi * 8);
      f32x4 c = {0.f, 0.f, 0.f, 0.f};
      c = __builtin_amdgcn_mfma_f32_16x16x32_bf16(a0, b0, c, 0, 0, 0);
      c = __builtin_amdgcn_mfma_f32_16x16x32_bf16(a1, b1, c, 0, 0, 0);
      acc[tt] = c;
    }
    #pragma unroll
    for (int sl = 0; sl < 4; sl++) {
      int r = rowbase + hi * 4 + sl;
      int pc = (r < T) ? (r + T) : (r - T);
      float v[4]; float vmax = NEG_BIG;
      #pragma unroll
      for (int tt = 0; tt < 4; tt++) {
        int cg = cb + tt * 16 + lo;
        float x = acc[tt][sl];
        if (r < TT && cg == pc) pos[sl] += x;
        bool excl = (cg >= TT) || (cg == r);
        x = excl ? NEG_BIG : x;
        v[tt] = x; vmax = fmaxf(vmax, x);
      }
      if (vmax > -1e29f) {
        float mn = fmaxf(m[sl], vmax);
        float ss = s[sl] * __expf(m[sl] - mn);
        #pragma unroll
        for (int tt = 0; tt < 4; tt++) ss += __expf(v[tt] - mn);
        s[sl] = ss; m[sl] = mn;
      }
    }
  }

  #pragma unroll
  for (int msk = 1; msk < 16; msk <<= 1) {
    #pragma unroll
    for (int sl = 0; sl < 4; sl++) {
      float mo = __shfl_xor(m[sl], msk, 16);
      float so = __shfl_xor(s[sl], msk, 16);
      float po = __shfl_xor(pos[sl], msk, 16);
      float mn = fmaxf(m[sl], mo);
      s[sl] = s[sl] * __expf(m[sl] - mn) + so * __expf(mo - mn);
      m[sl] = mn;
      pos[sl] += po;
    }
  }

  float val = 0.f;
  if (lo == 0) {
    #pragma unroll
    for (int sl = 0; sl < 4; sl++) {
      int r = rowbase + hi * 4 + sl;
      if (r < TT) val += m[sl] + __logf(s[sl]) - pos[sl];
    }
  }
  #pragma unroll
  for (int off = 32; off; off >>= 1) val += __shfl_down(val, off, 64);
  if (lane == 0) atomicAdd(out, val * scale);
}

// ---------------- host side ----------------
extern "C" void kernel_launch(void* const* d_in, const int* in_sizes, int n_in,
                              void* d_out, int out_size, void* d_ws, size_t ws_size,
                              hipStream_t stream)
{
  (void)in_sizes; (void)n_in; (void)out_size; (void)ws_size;
  const float* z1_0 = (const float*)d_in[0];
  const float* z2_0 = (const float*)d_in[1];
  const float* t_0  = (const float*)d_in[2];
  float* out = (float*)d_out;
  float* ws  = (float*)d_ws;

  const float* z1L[11]; const float* z2L[11]; const float* tL[11];
  float* z1Lw[11]; float* z2Lw[11]; float* tLw[11];
  z1L[0] = z1_0; z2L[0] = z2_0; tL[0] = t_0;
  size_t off = 0;
  for (int l = 1; l <= 10; l++) {
    int T = 1024 >> l;
    z1Lw[l] = ws + off; off += (size_t)16 * T * 64;
    z2Lw[l] = ws + off; off += (size_t)16 * T * 64;
    tLw[l]  = ws + off; off += (size_t)16 * T;
    z1L[l] = z1Lw[l]; z2L[l] = z2Lw[l]; tL[l] = tLw[l];
  }

  hipMemsetAsync(d_out, 0, sizeof(float), stream);

  const float inv_d = 1.0f / 11.0f;   // d = 11 levels
  for (int l = 0; l <= 10; l++) {
    int T = 1024 >> l;
    if (l > 0) {
      int total = 16 * T * 64 + 16 * T;
      int blocks = (total + 255) / 256;
      hipLaunchKernelGGL(downsample_kernel, dim3(blocks), dim3(256), 0, stream,
                         z1L[l - 1], z2L[l - 1], tL[l - 1], z1Lw[l], z2Lw[l], tLw[l], T);
    }
    int N = 16 * T;
    int lgT = 10 - l;
    float iscale = 0.5f * inv_d / (float)N;
    hipLaunchKernelGGL(instance_kernel, dim3((N + 63) / 64), dim3(256), 0, stream,
                       z1L[l], z2L[l], tL[l], out, T, lgT, iscale);
    if (T > 1) {
      float tscale = 0.5f * inv_d / (2.0f * 16.0f * (float)T);
      hipLaunchKernelGGL(temporal_kernel, dim3((2 * T + 63) / 64, 16), dim3(256), 0, stream,
                         z1L[l], z2L[l], out, T, tscale);
    }
  }
}

// Round 4
// 162.219 us; speedup vs baseline: 14.5724x; 3.7968x over previous
//
#include <hip/hip_runtime.h>
#include <hip/hip_bf16.h>
#include <math.h>

#define B_ 16
#define C_ 64
#define NEG_BIG (-1e30f)
#define POS_BIG (1e30f)

typedef __attribute__((ext_vector_type(8))) short bf16x8;
typedef __attribute__((ext_vector_type(4))) float f32x4;

__device__ __forceinline__ short f2bf(float x) {
  __hip_bfloat16 h = __float2bfloat16(x);
  return *reinterpret_cast<short*>(&h);
}

// ---- compile-time level tables (fixed problem size B=16,T=1024,C=64) ----
// temporal: levels l=0..9 (T=1024>>l >= 2); blocks/level = max(1,2T/64)*16
__device__ constexpr int kTS[10]   = {0, 512, 768, 896, 960, 992, 1008, 1024, 1040, 1056}; // starts, total 1072
__device__ constexpr int kZOff[10] = {0, 2097152, 3145728, 3670016, 3932160, 4063232,
                                      4128768, 4161536, 4177920, 4186112};                  // shorts
// instance: levels l=0..10; blocks/level = max(1,16T/64)
__device__ constexpr int kIS[11] = {0, 256, 384, 448, 480, 496, 504, 508, 510, 511, 512};   // total 513
// f32 pyramid offsets in ws (floats), l=1..10 (index 0 unused)
__device__ constexpr int kO1[11] = {0, 0, 1056768, 1585152, 1849344, 1981440, 2047488,
                                    2080512, 2097024, 2105280, 2109408};
__device__ constexpr int kO2[11] = {0, 524288, 1318912, 1716224, 1914880, 2014208, 2063872,
                                    2088704, 2101120, 2107328, 2110432};
__device__ constexpr int kOT[11] = {0, 1048576, 1581056, 1847296, 1980416, 2046976, 2080256,
                                    2096896, 2105216, 2109376, 2111456};

// ---------------- L0 f32 -> bf16 zc layout [b][2T][64] ----------------
__global__ __launch_bounds__(256) void convert0_kernel(
    const float* __restrict__ z1, const float* __restrict__ z2, short* __restrict__ zcb)
{
  int i = blockIdx.x * 256 + threadIdx.x;       // 131072 threads
  int n = i * 8;
  int b = n >> 16;                              // / (1024*64)
  float4 u1 = *(const float4*)(z1 + n), v1 = *(const float4*)(z1 + n + 4);
  float4 u2 = *(const float4*)(z2 + n), v2 = *(const float4*)(z2 + n + 4);
  bf16x8 f1, f2;
  f1[0]=f2bf(u1.x); f1[1]=f2bf(u1.y); f1[2]=f2bf(u1.z); f1[3]=f2bf(u1.w);
  f1[4]=f2bf(v1.x); f1[5]=f2bf(v1.y); f1[6]=f2bf(v1.z); f1[7]=f2bf(v1.w);
  f2[0]=f2bf(u2.x); f2[1]=f2bf(u2.y); f2[2]=f2bf(u2.z); f2[3]=f2bf(u2.w);
  f2[4]=f2bf(v2.x); f2[5]=f2bf(v2.y); f2[6]=f2bf(v2.z); f2[7]=f2bf(v2.w);
  *(bf16x8*)(zcb + (size_t)n + (size_t)b * 65536) = f1;
  *(bf16x8*)(zcb + (size_t)n + (size_t)(b + 1) * 65536) = f2;
}

// ---------------- pyramid downsample (+ bf16 zc of dest level) ----------------
__global__ __launch_bounds__(256) void downsample_kernel(
    const float* __restrict__ z1s, const float* __restrict__ z2s, const float* __restrict__ ts,
    float* __restrict__ z1d, float* __restrict__ z2d, float* __restrict__ td,
    short* __restrict__ zcb_l, int Td)
{
  int idx = blockIdx.x * blockDim.x + threadIdx.x;
  int total_z = B_ * Td * C_;
  if (idx < total_z) {
    int bi = idx >> 6;
    int b  = bi / Td;
    int s  = (b * (2 * Td) + 2 * (bi % Td)) * C_ + (idx & (C_ - 1));
    float v1 = fmaxf(z1s[s], z1s[s + C_]);
    float v2 = fmaxf(z2s[s], z2s[s + C_]);
    z1d[idx] = v1; z2d[idx] = v2;
    if (zcb_l) {
      int zi = idx + b * Td * C_;
      zcb_l[zi] = f2bf(v1);
      zcb_l[zi + Td * C_] = f2bf(v2);
    }
  } else {
    int k = idx - total_z;
    if (k < B_ * Td) {
      int i = k % Td, b = k / Td;
      int s = b * (2 * Td) + 2 * i;
      td[k] = 0.5f * (ts[s] + ts[s + 1]);
    }
  }
}

// ---------------- fused instance contrastive loss (all 11 levels) ----------------
__global__ __launch_bounds__(256) void instance_fused(
    const float* __restrict__ z1_0, const float* __restrict__ z2_0, const float* __restrict__ t_0,
    const float* __restrict__ ws, float* __restrict__ out)
{
  __shared__ float dmin[64 * 17], dLl[64 * 17], dRl[64 * 17];
  __shared__ int   Lp[64 * 17], Rp[64 * 17];
  __shared__ int   nbrs[64][16];

  int bid = blockIdx.x;
  int l = 0, ls = 0;
  #pragma unroll
  for (int i = 1; i < 11; i++) if (bid >= kIS[i]) { l = i; ls = kIS[i]; }
  int T = 1024 >> l, lgT = 10 - l, N = B_ * T;
  const float *z1, *z2, *t;
  if (l == 0) { z1 = z1_0; z2 = z2_0; t = t_0; }
  else {
    int i1 = 0, i2 = 0, it = 0;
    #pragma unroll
    for (int i = 1; i < 11; i++) if (l == i) { i1 = kO1[i]; i2 = kO2[i]; it = kOT[i]; }
    z1 = ws + i1; z2 = ws + i2; t = ws + it;
  }
  float scale = 0.5f / (11.0f * (float)N);

  int tid = threadIdx.x;
  int rbase = (bid - ls) * 64;

  if (T == 1) {
    for (int idx = tid; idx < 64 * 16; idx += 256)
      nbrs[idx >> 4][idx & 15] = idx & 15;
  } else {
    // ---- A0: 64 rows x 15 seqs parallel branchless searches ----
    for (int idx = tid; idx < 64 * 16; idx += 256) {
      int r = idx >> 4, s = idx & 15;
      int n = rbase + r;
      if (s < 15 && n < N) {
        int bq = n >> lgT;
        float q = t[n];
        int bs = s + (s >= bq ? 1 : 0);
        const float* tb = t + (bs << lgT);
        int li = 0;
        for (int k = T >> 1; k; k >>= 1) li += (tb[li + k - 1] < q) ? k : 0;
        li += (tb[li] < q) ? 1 : 0;
        float dl = (li >= 1) ? (q - tb[li - 1]) : POS_BIG;
        float dr = (li < T)  ? (tb[li] - q)     : POS_BIG;
        int o = r * 17 + s;
        Lp[o] = li - 1; Rp[o] = li;
        dLl[o] = dl; dRl[o] = dr; dmin[o] = fminf(dl, dr);
      }
    }
  }
  __syncthreads();

  int w = tid >> 6, lane = tid & 63;

  // ---- A1: per-row 16-step merge ----
  if (T > 1 && lane < 16) {
    int r = w * 16 + lane;
    int n = rbase + r;
    if (n < N) {
      int bq = n >> lgT;
      float q = t[n];
      #pragma unroll 1
      for (int j = 0; j < 16; j++) {
        float best = dmin[r * 17]; int sb = 0;
        #pragma unroll
        for (int s = 1; s < 15; s++) {
          float c = dmin[r * 17 + s];
          bool lt = c < best; best = lt ? c : best; sb = lt ? s : sb;
        }
        int o = r * 17 + sb;
        int bs = sb + (sb >= bq ? 1 : 0);
        float dl = dLl[o], dr = dRl[o];
        if (dl <= dr) {
          int p = Lp[o];
          nbrs[r][j] = bs * T + p;
          int pn = p - 1; Lp[o] = pn;
          float nd = (pn >= 0) ? (q - t[bs * T + pn]) : POS_BIG;
          dLl[o] = nd; dmin[o] = fminf(nd, dr);
        } else {
          int p = Rp[o];
          nbrs[r][j] = bs * T + p;
          int pn = p + 1; Rp[o] = pn;
          float nd = (pn < T) ? (t[bs * T + pn] - q) : POS_BIG;
          dRl[o] = nd; dmin[o] = fminf(dl, nd);
        }
      }
    } else {
      #pragma unroll
      for (int j = 0; j < 16; j++) nbrs[r][j] = 0;
    }
  }
  __syncthreads();

  // ---- B: wave-cooperative dots ----
  int g = lane >> 4, sl = lane & 15;
  float loss = 0.f;
  #pragma unroll 1
  for (int rc = 0; rc < 4; rc++) {
    int r = w * 16 + rc * 4 + g;
    int n = rbase + r;
    bool act = n < N;
    int ns = act ? n : rbase;
    float4 za = *(const float4*)(z1 + (size_t)ns * C_ + sl * 4);
    float4 zp = *(const float4*)(z2 + (size_t)ns * C_ + sl * 4);
    float pos = za.x * zp.x + za.y * zp.y + za.z * zp.z + za.w * zp.w;
    float a11[16], a12[16];
    #pragma unroll
    for (int j = 0; j < 16; j++) {
      int nb = nbrs[r][j];
      float4 uu = *(const float4*)(z1 + (size_t)nb * C_ + sl * 4);
      float4 vv = *(const float4*)(z2 + (size_t)nb * C_ + sl * 4);
      a11[j] = za.x * uu.x + za.y * uu.y + za.z * uu.z + za.w * uu.w;
      a12[j] = za.x * vv.x + za.y * vv.y + za.z * vv.z + za.w * vv.w;
    }
    #pragma unroll
    for (int msk = 1; msk < 16; msk <<= 1) {
      pos += __shfl_xor(pos, msk, 16);
      #pragma unroll
      for (int j = 0; j < 16; j++) {
        a11[j] += __shfl_xor(a11[j], msk, 16);
        a12[j] += __shfl_xor(a12[j], msk, 16);
      }
    }
    if (sl == 0 && act) {
      float m = pos;
      #pragma unroll
      for (int j = 0; j < 16; j++) m = fmaxf(m, fmaxf(a11[j], a12[j]));
      float se = __expf(pos - m);
      #pragma unroll
      for (int j = 0; j < 16; j++) se += __expf(a11[j] - m) + __expf(a12[j] - m);
      loss += (m + __logf(se)) - pos;
    }
  }
  #pragma unroll
  for (int off = 32; off; off >>= 1) loss += __shfl_down(loss, off, 64);
  if (lane == 0) atomicAdd(out, loss * scale);
}

// ---------------- fused temporal contrastive loss (levels 0..9), bf16 MFMA ----------------
// Block = 64 rows x full column sweep; B-chunks (64x64 bf16) staged in swizzled LDS,
// shared by 4 waves; async stage (load ch+1 under compute of ch); pos hoisted to epilogue.
__global__ __launch_bounds__(256) void temporal_fused(
    const float* __restrict__ z1_0, const float* __restrict__ z2_0,
    const float* __restrict__ ws, const short* __restrict__ zcb, float* __restrict__ out)
{
  __shared__ __align__(16) short sb[64 * 64];   // 8KB, XOR-swizzled rows

  // bijective XCD swizzle: 1072 = 8 * 134
  int orig = blockIdx.x;
  int bid = (orig & 7) * 134 + (orig >> 3);

  int l = 0, ls = 0;
  #pragma unroll
  for (int i = 1; i < 10; i++) if (bid >= kTS[i]) { l = i; ls = kTS[i]; }
  int T = 1024 >> l, TT = 2 * T;
  int lb = bid - ls;
  int lg = (5 - l) > 0 ? (5 - l) : 0;           // log2(row-blocks per batch)
  int b = lb >> lg, rblk = lb & ((1 << lg) - 1);

  int zoff = 0, fo1 = 0, fo2 = 0;
  #pragma unroll
  for (int i = 1; i < 10; i++) if (l == i) { zoff = kZOff[i]; fo1 = kO1[i]; fo2 = kO2[i]; }
  const short* zl = zcb + zoff + (size_t)b * TT * C_;
  const float* z1b = ((l == 0) ? z1_0 : ws + fo1) + (size_t)b * T * C_;
  const float* z2b = ((l == 0) ? z2_0 : ws + fo2) + (size_t)b * T * C_;

  int tid = threadIdx.x;
  int wv = tid >> 6, lane = tid & 63, lo = lane & 15, hi = lane >> 4;
  int rowbase = rblk * 64 + wv * 16;
  bool activew = rowbase < TT;
  int diagch = rowbase >> 6;

  // A fragments (global gather, once); symmetric-layout trick: same lane->(row,k) map as B
  int ar = rowbase + lo; if (ar >= TT) ar = TT - 1;
  const short* pa = zl + (size_t)ar * C_;
  bf16x8 a0 = *(const bf16x8*)(pa + hi * 8);
  bf16x8 a1 = *(const bf16x8*)(pa + 32 + hi * 8);

  float m[4], s[4];
  #pragma unroll
  for (int sl = 0; sl < 4; sl++) { m[sl] = NEG_BIG; s[sl] = 0.f; }

  // staging geometry: 512 x 16B chunks, 2 per thread; write-side swizzle
  int c0 = tid, c1 = tid + 256;
  int r0 = c0 >> 3, s0 = c0 & 7, r1 = c1 >> 3, s1 = c1 & 7;
  int swb0 = r0 * 128 + ((s0 * 16) ^ ((r0 & 7) << 4));
  int swb1 = r1 * 128 + ((s1 * 16) ^ ((r1 & 7) << 4));

  int nch = (TT + 63) >> 6;
  int rr0 = r0, rr1 = r1;  // chunk-local rows
  // load chunk 0
  int q0 = rr0; if (q0 >= TT) q0 = TT - 1;
  int q1 = rr1; if (q1 >= TT) q1 = TT - 1;
  float4 st0 = *(const float4*)(zl + (size_t)q0 * C_ + s0 * 8);
  float4 st1 = *(const float4*)(zl + (size_t)q1 * C_ + s1 * 8);

  for (int ch = 0; ch < nch; ch++) {
    int cb = ch << 6;
    __syncthreads();                                   // sb free
    *(float4*)((char*)sb + swb0) = st0;
    *(float4*)((char*)sb + swb1) = st1;
    __syncthreads();                                   // staged visible
    if (ch + 1 < nch) {
      int nb0 = cb + 64 + rr0; if (nb0 >= TT) nb0 = TT - 1;
      int nb1 = cb + 64 + rr1; if (nb1 >= TT) nb1 = TT - 1;
      st0 = *(const float4*)(zl + (size_t)nb0 * C_ + s0 * 8);
      st1 = *(const float4*)(zl + (size_t)nb1 * C_ + s1 * 8);
    }
    if (activew) {
      f32x4 acc[4];
      #pragma unroll
      for (int tt = 0; tt < 4; tt++) {
        int br = tt * 16 + lo;
        int byt = br * 128 + ((hi * 16) ^ ((br & 7) << 4));
        bf16x8 b0 = *(const bf16x8*)((const char*)sb + byt);
        bf16x8 b1 = *(const bf16x8*)((const char*)sb + (byt ^ 64));
        f32x4 c = {0.f, 0.f, 0.f, 0.f};
        c = __builtin_amdgcn_mfma_f32_16x16x32_bf16(a0, b0, c, 0, 0, 0);
        c = __builtin_amdgcn_mfma_f32_16x16x32_bf16(a1, b1, c, 0, 0, 0);
        acc[tt] = c;
      }
      bool maskpath = (ch == diagch) || (cb + 64 > TT);
      if (maskpath) {
        #pragma unroll
        for (int sl = 0; sl < 4; sl++) {
          int r = rowbase + hi * 4 + sl;
          float v[4]; float vmax = NEG_BIG;
          #pragma unroll
          for (int tt = 0; tt < 4; tt++) {
            int cg = cb + tt * 16 + lo;
            bool excl = (cg >= TT) || (cg == r);
            v[tt] = excl ? NEG_BIG : acc[tt][sl];
            vmax = fmaxf(vmax, v[tt]);
          }
          if (vmax > -1e29f) {
            float mn = fmaxf(m[sl], vmax);
            float ss = s[sl] * __expf(m[sl] - mn);
            #pragma unroll
            for (int tt = 0; tt < 4; tt++) ss += __expf(v[tt] - mn);
            s[sl] = ss; m[sl] = mn;
          }
        }
      } else {
        #pragma unroll
        for (int sl = 0; sl < 4; sl++) {
          float vmax = fmaxf(fmaxf(acc[0][sl], acc[1][sl]), fmaxf(acc[2][sl], acc[3][sl]));
          float mn = fmaxf(m[sl], vmax);
          float ss = s[sl] * __expf(m[sl] - mn);
          #pragma unroll
          for (int tt = 0; tt < 4; tt++) ss += __expf(acc[tt][sl] - mn);
          s[sl] = ss; m[sl] = mn;
        }
      }
    }
  }

  // pos from f32 (lane lo covers channels lo*4..lo*4+3; merged in butterfly below)
  float pos[4] = {0.f, 0.f, 0.f, 0.f};
  if (activew) {
    #pragma unroll
    for (int sl = 0; sl < 4; sl++) {
      int r = rowbase + hi * 4 + sl;
      if (r < TT) {
        int rr = (r < T) ? r : r - T;
        float4 u = *(const float4*)(z1b + (size_t)rr * C_ + lo * 4);
        float4 v = *(const float4*)(z2b + (size_t)rr * C_ + lo * 4);
        pos[sl] = u.x * v.x + u.y * v.y + u.z * v.z + u.w * v.w;
      }
    }
  }

  #pragma unroll
  for (int msk = 1; msk < 16; msk <<= 1) {
    #pragma unroll
    for (int sl = 0; sl < 4; sl++) {
      float mo = __shfl_xor(m[sl], msk, 16);
      float so = __shfl_xor(s[sl], msk, 16);
      float po = __shfl_xor(pos[sl], msk, 16);
      float mn = fmaxf(m[sl], mo);
      s[sl] = s[sl] * __expf(m[sl] - mn) + so * __expf(mo - mn);
      m[sl] = mn;
      pos[sl] += po;
    }
  }

  float val = 0.f;
  if (lo == 0 && activew) {
    #pragma unroll
    for (int sl = 0; sl < 4; sl++) {
      int r = rowbase + hi * 4 + sl;
      if (r < TT) val += m[sl] + __logf(s[sl]) - pos[sl];
    }
  }
  #pragma unroll
  for (int off = 32; off; off >>= 1) val += __shfl_down(val, off, 64);
  float tscale = 0.5f / (11.0f * 2.0f * 16.0f * (float)T);
  if (lane == 0) atomicAdd(out, val * tscale);
}

// ---------------- host side ----------------
extern "C" void kernel_launch(void* const* d_in, const int* in_sizes, int n_in,
                              void* d_out, int out_size, void* d_ws, size_t ws_size,
                              hipStream_t stream)
{
  (void)in_sizes; (void)n_in; (void)out_size; (void)ws_size;
  const float* z1_0 = (const float*)d_in[0];
  const float* z2_0 = (const float*)d_in[1];
  const float* t_0  = (const float*)d_in[2];
  float* out = (float*)d_out;
  float* ws  = (float*)d_ws;

  // f32 pyramid (levels 1..10)
  float* o1[11]; float* o2[11]; float* ot[11];
  size_t off = 0;
  for (int l = 1; l <= 10; l++) {
    int T = 1024 >> l;
    o1[l] = ws + off; off += (size_t)16 * T * 64;
    o2[l] = ws + off; off += (size_t)16 * T * 64;
    ot[l] = ws + off; off += (size_t)16 * T;
  }
  // bf16 zc pyramid (levels 0..9)
  short* zcb = (short*)(ws + off);
  short* zl[10]; size_t zo = 0;
  for (int l = 0; l <= 9; l++) {
    zl[l] = zcb + zo; zo += (size_t)16 * 2 * (1024 >> l) * 64;
  }

  hipMemsetAsync(d_out, 0, sizeof(float), stream);

  hipLaunchKernelGGL(convert0_kernel, dim3(512), dim3(256), 0, stream, z1_0, z2_0, zl[0]);
  for (int l = 1; l <= 10; l++) {
    int T = 1024 >> l;
    int total = 16 * T * 64 + 16 * T;
    int blocks = (total + 255) / 256;
    hipLaunchKernelGGL(downsample_kernel, dim3(blocks), dim3(256), 0, stream,
                       (l == 1) ? z1_0 : o1[l - 1], (l == 1) ? z2_0 : o2[l - 1],
                       (l == 1) ? t_0 : ot[l - 1],
                       o1[l], o2[l], ot[l], (l <= 9) ? zl[l] : (short*)nullptr, T);
  }
  hipLaunchKernelGGL(instance_fused, dim3(513), dim3(256), 0, stream,
                     z1_0, z2_0, t_0, ws, out);
  hipLaunchKernelGGL(temporal_fused, dim3(1072), dim3(256), 0, stream,
                     z1_0, z2_0, ws, zcb, out);
}